// Round 1
// baseline (100.789 us; speedup 1.0000x reference)
//
#include <hip/hip_runtime.h>

#define N_IMG 16
#define M_GT 128
#define P_PROP 8192
#define NUM_CLASSES 80
#define THREADS 256

// One thread per (image, proposal). GT data staged in LDS (broadcast reads).
// IoU arithmetic replicates the JAX reference op-for-op in f32 so that
// argmax tie-breaking (first occurrence of max, strict '>' ascending scan)
// matches bit-exactly.
__global__ __launch_bounds__(THREADS) void roi_match_kernel(
    const float* __restrict__ gt_boxes,    // [N, M, 4]
    const float* __restrict__ pr_boxes,    // [N, P, 4]
    const int*   __restrict__ gt_classes,  // [N, M] int32
    const void*  __restrict__ gt_ignores,  // [N, M] bool -- storage detected
    float* __restrict__ out)               // [iou | idx | labels | classes] as f32
{
    __shared__ float s_x1[M_GT], s_y1[M_GT], s_x2[M_GT], s_y2[M_GT], s_ag[M_GT];
    __shared__ int   s_cls[M_GT], s_ign[M_GT];
    __shared__ int   s_b01, s_bf;

    const int tid = threadIdx.x;
    const int n   = blockIdx.x >> 5;                    // / (P/THREADS) = /32
    const int p   = ((blockIdx.x & 31) << 8) + tid;

    // ---- detect gt_ignores storage: 0 = int32, 1 = uint8, 2 = float32 ----
    if (tid == 0) { s_b01 = 0; s_bf = 0; }
    __syncthreads();
    {
        const int* w = (const int*)gt_ignores;
        int bad01 = 0, badf = 0;
        // 512 words = 2048 bytes: safe lower bound for all candidate widths.
        for (int i = tid; i < 512; i += THREADS) {
            int v = w[i];
            bad01 |= (v != 0) & (v != 1);
            badf  |= (v != 0) & (v != 0x3F800000);
        }
        if (bad01) atomicOr(&s_b01, 1);
        if (badf)  atomicOr(&s_bf, 1);
    }
    __syncthreads();
    const int mode = s_b01 ? (s_bf ? 1 : 2) : 0;

    // ---- stage GT data for this image ----
    for (int m = tid; m < M_GT; m += THREADS) {
        const float4 g = *reinterpret_cast<const float4*>(gt_boxes + ((size_t)n * M_GT + m) * 4);
        s_x1[m] = g.x; s_y1[m] = g.y; s_x2[m] = g.z; s_y2[m] = g.w;
        s_ag[m] = (g.z - g.x) * (g.w - g.y);            // area_g, same op order as ref
        s_cls[m] = gt_classes[n * M_GT + m];
        int ig;
        if (mode == 0)      ig = ((const int*)gt_ignores)[n * M_GT + m] != 0;
        else if (mode == 1) ig = ((const unsigned char*)gt_ignores)[n * M_GT + m] != 0;
        else                ig = ((const float*)gt_ignores)[n * M_GT + m] != 0.0f;
        s_ign[m] = ig;
    }
    __syncthreads();

    // ---- per-proposal work ----
    const float4 pv = *reinterpret_cast<const float4*>(pr_boxes + ((size_t)n * P_PROP + p) * 4);
    const float px1 = pv.x, py1 = pv.y, px2 = pv.z, py2 = pv.w;
    const float area_p = (px2 - px1) * (py2 - py1);

    float best  = -1.0f;      // all IoUs >= 0, so first m always wins initially
    int   bidx  = 0;
    float maxig = -1e30f;

    float* iou_out = out + (size_t)(n * M_GT) * P_PROP + p;

#pragma unroll 8
    for (int m = 0; m < M_GT; ++m) {
        // exact replication of reference arithmetic (f32, no fma-contractable ops)
        const float lx = fmaxf(s_x1[m], px1);
        const float ly = fmaxf(s_y1[m], py1);
        const float rx = fminf(s_x2[m], px2);
        const float ry = fminf(s_y2[m], py2);
        const float w  = fmaxf(rx - lx, 0.0f);
        const float h  = fmaxf(ry - ly, 0.0f);
        const float inter = w * h;
        const float uni   = s_ag[m] + area_p - inter;   // (area_g + area_p) - inter
        const float iou   = (inter > 0.0f) ? inter / fmaxf(uni, 1e-9f) : 0.0f;

        iou_out[(size_t)m * P_PROP] = iou;

        if (iou > best) { best = iou; bidx = m; }       // first-max tie-break == jnp.argmax
        if (s_ign[m]) maxig = fmaxf(maxig, iou);
    }

    // matcher labels: 1 fg / -1 ignore / 0 bg, then ignored-GT override
    int label = (best >= 0.7f) ? 1 : ((best >= 0.3f) ? -1 : 0);
    if (maxig > 0.7f) label = -1;

    int cls = s_cls[bidx];
    if (label == 0)  cls = NUM_CLASSES;
    if (label == -1) cls = -1;

    const size_t base = (size_t)N_IMG * M_GT * P_PROP;
    const int np = n * P_PROP + p;
    out[base + np]                      = (float)bidx;
    out[base + (size_t)N_IMG * P_PROP + np]     = (float)label;
    out[base + (size_t)2 * N_IMG * P_PROP + np] = (float)cls;
}

extern "C" void kernel_launch(void* const* d_in, const int* in_sizes, int n_in,
                              void* d_out, int out_size, void* d_ws, size_t ws_size,
                              hipStream_t stream) {
    const float* gt_boxes   = (const float*)d_in[0];
    const float* pr_boxes   = (const float*)d_in[1];
    const int*   gt_classes = (const int*)d_in[2];
    const void*  gt_ignores = (const void*)d_in[3];
    float* out = (float*)d_out;

    const int blocks = N_IMG * (P_PROP / THREADS);  // 16 * 32 = 512
    roi_match_kernel<<<blocks, THREADS, 0, stream>>>(
        gt_boxes, pr_boxes, gt_classes, gt_ignores, out);
}

// Round 2
// 96.733 us; speedup vs baseline: 1.0419x; 1.0419x over previous
//
#include <hip/hip_runtime.h>

#define N_IMG 16
#define M_GT 128
#define P_PROP 8192
#define NUM_CLASSES 80
#define THREADS 256

#define QUARTERS 4
#define MQ (M_GT / QUARTERS)      // 32 GTs per quarter
#define PPT 2                     // proposals per thread
#define PBLK (THREADS * PPT)      // 512 proposals per block
#define NPBLK (P_PROP / PBLK)     // 16 p-chunks per image
#define NP (N_IMG * P_PROP)       // 131072

// ---------------- main kernel: iou writes + per-quarter partials ----------------
// grid: blockIdx.x = ((n * NPBLK) + pblk) * QUARTERS + q   -> 16*16*4 = 1024 blocks
__global__ __launch_bounds__(THREADS) void iou_kernel(
    const float* __restrict__ gt_boxes,    // [N, M, 4]
    const float* __restrict__ pr_boxes,    // [N, P, 4]
    const void*  __restrict__ gt_ignores,  // [N, M] bool (storage detected)
    float* __restrict__ out,               // iou [N, M, P] at offset 0
    float* __restrict__ ws)                // partials: val/arg/ig each [Q][N*P]
{
    __shared__ float4 s_box[MQ];
    __shared__ float  s_ag[MQ];
    __shared__ int    s_ign[MQ];
    __shared__ int    s_b01, s_bf;

    const int tid  = threadIdx.x;
    const int q    = blockIdx.x & 3;
    const int pblk = (blockIdx.x >> 2) & (NPBLK - 1);
    const int n    = blockIdx.x >> 6;

    // ---- detect gt_ignores storage: 0 = int32, 1 = uint8, 2 = float32 ----
    if (tid == 0) { s_b01 = 0; s_bf = 0; }
    __syncthreads();
    {
        const int* w = (const int*)gt_ignores;
        int bad01 = 0, badf = 0;
        for (int i = tid; i < 512; i += THREADS) {   // 2048 bytes: safe for all widths
            int v = w[i];
            bad01 |= (v != 0) & (v != 1);
            badf  |= (v != 0) & (v != 0x3F800000);
        }
        if (bad01) atomicOr(&s_b01, 1);
        if (badf)  atomicOr(&s_bf, 1);
    }
    __syncthreads();
    const int mode = s_b01 ? (s_bf ? 1 : 2) : 0;

    // ---- stage this quarter's GT data ----
    if (tid < MQ) {
        const int m = q * MQ + tid;
        const float4 g = *reinterpret_cast<const float4*>(gt_boxes + ((size_t)n * M_GT + m) * 4);
        s_box[tid] = g;
        s_ag[tid]  = (g.z - g.x) * (g.w - g.y);   // same op order as reference
        int ig;
        if (mode == 0)      ig = ((const int*)gt_ignores)[n * M_GT + m] != 0;
        else if (mode == 1) ig = ((const unsigned char*)gt_ignores)[n * M_GT + m] != 0;
        else                ig = ((const float*)gt_ignores)[n * M_GT + m] != 0.0f;
        s_ign[tid] = ig;
    }
    __syncthreads();

    // ---- two proposals per thread ----
    const int p0 = pblk * PBLK + tid * PPT;
    const float4 pa = *reinterpret_cast<const float4*>(pr_boxes + ((size_t)n * P_PROP + p0) * 4);
    const float4 pb = *reinterpret_cast<const float4*>(pr_boxes + ((size_t)n * P_PROP + p0 + 1) * 4);
    const float area_a = (pa.z - pa.x) * (pa.w - pa.y);
    const float area_b = (pb.z - pb.x) * (pb.w - pb.y);

    float best_a = -1.0f, best_b = -1.0f;
    int   arg_a  = 0,     arg_b  = 0;
    float ig_a   = -1e30f, ig_b  = -1e30f;

    float* iou_out = out + ((size_t)(n * M_GT + q * MQ)) * P_PROP + p0;

#pragma unroll 8
    for (int mi = 0; mi < MQ; ++mi) {
        const float4 g  = s_box[mi];
        const float  ag = s_ag[mi];
        const int    ig = s_ign[mi];
        const int    m  = q * MQ + mi;

        // proposal a  (exact reference arithmetic, f32, first-max tie-break)
        float lx = fmaxf(g.x, pa.x), ly = fmaxf(g.y, pa.y);
        float rx = fminf(g.z, pa.z), ry = fminf(g.w, pa.w);
        float w  = fmaxf(rx - lx, 0.0f), h = fmaxf(ry - ly, 0.0f);
        float inter = w * h;
        float uni   = ag + area_a - inter;
        float iou_a = (inter > 0.0f) ? inter / fmaxf(uni, 1e-9f) : 0.0f;

        // proposal b
        lx = fmaxf(g.x, pb.x); ly = fmaxf(g.y, pb.y);
        rx = fminf(g.z, pb.z); ry = fminf(g.w, pb.w);
        w  = fmaxf(rx - lx, 0.0f); h = fmaxf(ry - ly, 0.0f);
        inter = w * h;
        uni   = ag + area_b - inter;
        float iou_b = (inter > 0.0f) ? inter / fmaxf(uni, 1e-9f) : 0.0f;

        *reinterpret_cast<float2*>(iou_out) = make_float2(iou_a, iou_b);
        iou_out += P_PROP;

        if (iou_a > best_a) { best_a = iou_a; arg_a = m; }
        if (iou_b > best_b) { best_b = iou_b; arg_b = m; }
        if (ig) { ig_a = fmaxf(ig_a, iou_a); ig_b = fmaxf(ig_b, iou_b); }
    }

    // ---- per-quarter partials to workspace ----
    const size_t idx = (size_t)q * NP + (size_t)n * P_PROP + p0;
    float* wval = ws;
    float* warg = ws + (size_t)QUARTERS * NP;
    float* wig  = ws + (size_t)2 * QUARTERS * NP;
    *reinterpret_cast<float2*>(wval + idx) = make_float2(best_a, best_b);
    *reinterpret_cast<float2*>(warg + idx) = make_float2((float)arg_a, (float)arg_b);
    *reinterpret_cast<float2*>(wig  + idx) = make_float2(ig_a, ig_b);
}

// ---------------- reduce kernel: combine quarters, labels, classes ----------------
__global__ __launch_bounds__(THREADS) void reduce_kernel(
    const float* __restrict__ ws,
    const int*   __restrict__ gt_classes,  // [N, M]
    float* __restrict__ out)
{
    const int t = blockIdx.x * THREADS + threadIdx.x;   // 0 .. NP-1
    const int n = t >> 13;                               // / P_PROP

    const float* wval = ws;
    const float* warg = ws + (size_t)QUARTERS * NP;
    const float* wig  = ws + (size_t)2 * QUARTERS * NP;

    float best = -1.0f, barg = 0.0f, mig = -1e30f;
#pragma unroll
    for (int q = 0; q < QUARTERS; ++q) {                 // ascending: first-max wins
        const float v = wval[(size_t)q * NP + t];
        const float a = warg[(size_t)q * NP + t];
        const float g = wig [(size_t)q * NP + t];
        if (v > best) { best = v; barg = a; }
        mig = fmaxf(mig, g);
    }

    int label = (best >= 0.7f) ? 1 : ((best >= 0.3f) ? -1 : 0);
    if (mig > 0.7f) label = -1;

    int cls = gt_classes[n * M_GT + (int)barg];
    if (label == 0)  cls = NUM_CLASSES;
    if (label == -1) cls = -1;

    const size_t base = (size_t)N_IMG * M_GT * P_PROP;
    out[base + t]            = barg;
    out[base + NP + t]       = (float)label;
    out[base + 2 * (size_t)NP + t] = (float)cls;
}

extern "C" void kernel_launch(void* const* d_in, const int* in_sizes, int n_in,
                              void* d_out, int out_size, void* d_ws, size_t ws_size,
                              hipStream_t stream) {
    const float* gt_boxes   = (const float*)d_in[0];
    const float* pr_boxes   = (const float*)d_in[1];
    const int*   gt_classes = (const int*)d_in[2];
    const void*  gt_ignores = (const void*)d_in[3];
    float* out = (float*)d_out;
    float* ws  = (float*)d_ws;

    const int blocks_main = N_IMG * NPBLK * QUARTERS;   // 1024
    iou_kernel<<<blocks_main, THREADS, 0, stream>>>(gt_boxes, pr_boxes, gt_ignores, out, ws);

    const int blocks_red = NP / THREADS;                // 512
    reduce_kernel<<<blocks_red, THREADS, 0, stream>>>(ws, gt_classes, out);
}